// Round 1
// baseline (1154.648 us; speedup 1.0000x reference)
//
#include <hip/hip_runtime.h>
#include <hip/hip_bf16.h>

// SimpleMetaConvKALN: x (64,64,64,64) f32, w (32,80,3,3) f32 -> out (64,128,64,64) f32
// 4 groups of 16 in-ch -> 32 out-ch each. Augmented-input view:
//   A[0:16]=silu(x), A[16:32]=1, A[32:48]=xn, A[48:64]=P2(xn), A[64:80]=P3(xn)
//   y = conv3x3(A, w) ; then instance-norm over HxW per (b,oc) ; then silu.

#define NB 64
#define NH 64
#define NW 64

__device__ __forceinline__ unsigned fmap(float f) {
    unsigned u = __float_as_uint(f);
    return (u & 0x80000000u) ? ~u : (u | 0x80000000u);
}
__device__ __forceinline__ float funmap(unsigned m) {
    unsigned u = (m & 0x80000000u) ? (m ^ 0x80000000u) : ~m;
    return __uint_as_float(u);
}
__device__ __forceinline__ float silu(float v) {
    return v / (1.0f + __expf(-v));
}

__global__ void init_ws_kernel(unsigned* ws) {
    int t = threadIdx.x;
    if (t < 4) { ws[t * 2] = 0xFFFFFFFFu; ws[t * 2 + 1] = 0u; }
}

__global__ __launch_bounds__(256) void minmax_kernel(const float* __restrict__ x,
                                                     unsigned* __restrict__ ws) {
    // one block per (b,ch) plane of 4096 floats
    int plane = blockIdx.x;          // b*64 + ch
    int ch = plane & 63;
    int g = ch >> 4;
    const float4* p = (const float4*)(x + (size_t)plane * 4096);
    int t = threadIdx.x;
    float mn = 3.4e38f, mx = -3.4e38f;
    #pragma unroll
    for (int k = 0; k < 4; ++k) {
        float4 v = p[t + k * 256];
        mn = fminf(mn, fminf(fminf(v.x, v.y), fminf(v.z, v.w)));
        mx = fmaxf(mx, fmaxf(fmaxf(v.x, v.y), fmaxf(v.z, v.w)));
    }
    #pragma unroll
    for (int off = 32; off; off >>= 1) {
        mn = fminf(mn, __shfl_xor(mn, off));
        mx = fmaxf(mx, __shfl_xor(mx, off));
    }
    __shared__ float smn[4], smx[4];
    int wid = t >> 6, lane = t & 63;
    if (lane == 0) { smn[wid] = mn; smx[wid] = mx; }
    __syncthreads();
    if (t == 0) {
        mn = fminf(fminf(smn[0], smn[1]), fminf(smn[2], smn[3]));
        mx = fmaxf(fmaxf(smx[0], smx[1]), fmaxf(smx[2], smx[3]));
        atomicMin(&ws[g * 2], fmap(mn));
        atomicMax(&ws[g * 2 + 1], fmap(mx));
    }
}

__global__ __launch_bounds__(256) void conv_kernel(const float* __restrict__ x,
                                                   const float* __restrict__ wgt,
                                                   const unsigned* __restrict__ ws,
                                                   float* __restrict__ out) {
    int tile = blockIdx.x;   // 0..15 -> 4x4 tiles of 16x16
    int b = blockIdx.y;
    int g = blockIdx.z;
    int th0 = (tile >> 2) * 16, tw0 = (tile & 3) * 16;
    float xmin = funmap(ws[g * 2]);
    float xmax = funmap(ws[g * 2 + 1]);
    float inv = 2.0f / (xmax - xmin);   // xn = (x - xmin)*inv - 1

    __shared__ float lds[5][18][20];    // stride 20 to dodge bank conflicts
    float acc[32];
    #pragma unroll
    for (int i = 0; i < 32; ++i) acc[i] = 0.f;

    int t = threadIdx.x;
    int ty = t >> 4, tx = t & 15;
    const float* xg = x + ((size_t)b * 64 + g * 16) * 4096;

    for (int c = 0; c < 16; ++c) {
        __syncthreads();   // readers of previous iter done before overwrite
        for (int e = t; e < 324; e += 256) {
            int ly = e / 18, lx = e - ly * 18;
            int gh = th0 + ly - 1, gw = tw0 + lx - 1;
            bool ok = (gh >= 0 && gh < NH && gw >= 0 && gw < NW);
            float v = ok ? xg[c * 4096 + gh * 64 + gw] : 0.f;
            float s  = silu(v);                  // silu(0)=0 so OOB fine
            float xn = (v - xmin) * inv - 1.f;
            float p2 = 1.5f * xn * xn - 0.5f;
            float p3 = (2.5f * xn * xn - 1.5f) * xn;
            lds[0][ly][lx] = s;
            lds[1][ly][lx] = ok ? 1.f : 0.f;     // zero-padded ones channel
            lds[2][ly][lx] = ok ? xn : 0.f;
            lds[3][ly][lx] = ok ? p2 : 0.f;
            lds[4][ly][lx] = ok ? p3 : 0.f;
        }
        __syncthreads();

        float in[5][9];
        #pragma unroll
        for (int d = 0; d < 5; ++d)
            #pragma unroll
            for (int ky = 0; ky < 3; ++ky)
                #pragma unroll
                for (int kx = 0; kx < 3; ++kx)
                    in[d][ky * 3 + kx] = lds[d][ty + ky][tx + kx];

        // w[oc][ic][ky][kx], ic = d*16 + c  -> off = oc*720 + d*144 + c*9 + tap
        const float* wc = wgt + (size_t)c * 9;
        #pragma unroll
        for (int oc = 0; oc < 32; ++oc) {
            #pragma unroll
            for (int d = 0; d < 5; ++d) {
                const float* wp = wc + oc * 720 + d * 144;
                #pragma unroll
                for (int tap = 0; tap < 9; ++tap)
                    acc[oc] = fmaf(in[d][tap], wp[tap], acc[oc]);
            }
        }
    }

    size_t base = ((size_t)b * 128 + g * 32) * 4096 + (size_t)(th0 + ty) * 64 + (tw0 + tx);
    #pragma unroll
    for (int oc = 0; oc < 32; ++oc)
        out[base + (size_t)oc * 4096] = acc[oc];
}

__global__ __launch_bounds__(256) void norm_kernel(float* __restrict__ out) {
    int plane = blockIdx.x;      // b*128 + ch
    float4* p = (float4*)(out + (size_t)plane * 4096);
    int t = threadIdx.x;
    float4 v[4];
    float s = 0.f, s2 = 0.f;
    #pragma unroll
    for (int k = 0; k < 4; ++k) {
        v[k] = p[t + k * 256];
        s  += v[k].x + v[k].y + v[k].z + v[k].w;
        s2 += v[k].x * v[k].x + v[k].y * v[k].y + v[k].z * v[k].z + v[k].w * v[k].w;
    }
    #pragma unroll
    for (int off = 32; off; off >>= 1) {
        s  += __shfl_xor(s, off);
        s2 += __shfl_xor(s2, off);
    }
    __shared__ float ss[4], ss2[4];
    int wid = t >> 6, lane = t & 63;
    if (lane == 0) { ss[wid] = s; ss2[wid] = s2; }
    __syncthreads();
    s  = ss[0] + ss[1] + ss[2] + ss[3];
    s2 = ss2[0] + ss2[1] + ss2[2] + ss2[3];
    float mean = s * (1.f / 4096.f);
    float var  = fmaxf(s2 * (1.f / 4096.f) - mean * mean, 0.f);
    float istd = rsqrtf(var + 1e-5f);
    #pragma unroll
    for (int k = 0; k < 4; ++k) {
        float4 o;
        o.x = (v[k].x - mean) * istd; o.x = silu(o.x);
        o.y = (v[k].y - mean) * istd; o.y = silu(o.y);
        o.z = (v[k].z - mean) * istd; o.z = silu(o.z);
        o.w = (v[k].w - mean) * istd; o.w = silu(o.w);
        p[t + k * 256] = o;
    }
}

extern "C" void kernel_launch(void* const* d_in, const int* in_sizes, int n_in,
                              void* d_out, int out_size, void* d_ws, size_t ws_size,
                              hipStream_t stream) {
    const float* x = (const float*)d_in[0];
    const float* w = (const float*)d_in[1];
    float* out = (float*)d_out;
    unsigned* ws = (unsigned*)d_ws;

    hipLaunchKernelGGL(init_ws_kernel, dim3(1), dim3(64), 0, stream, ws);
    hipLaunchKernelGGL(minmax_kernel, dim3(NB * 64), dim3(256), 0, stream, x, ws);
    hipLaunchKernelGGL(conv_kernel, dim3(16, NB, 4), dim3(256), 0, stream, x, w, ws, out);
    hipLaunchKernelGGL(norm_kernel, dim3(NB * 128), dim3(256), 0, stream, out);
}

// Round 2
// 277.183 us; speedup vs baseline: 4.1657x; 4.1657x over previous
//
#include <hip/hip_runtime.h>
#include <hip/hip_bf16.h>

// SimpleMetaConvKALN: x (64,64,64,64) f32, w (32,80,3,3) f32 -> out (64,128,64,64) f32
// Augmented-input view per group g (16 in-ch):
//   A[0:16]=silu(x), A[16:32]=1, A[32:48]=xn, A[48:64]=P2(xn), A[64:80]=P3(xn)
//   y = conv3x3(A, w) == sum over 9 taps of shifted GEMM (M=px, N=32 oc, K=80)
//   then instance-norm over HxW per (b,oc), then silu.
// bf16 MFMA path: mfma_f32_32x32x16_bf16, A staged in LDS (K-padded to 88),
// weights repacked to [tap][oc][k] bf16 in d_ws.

#define NB 64
#define NH 64
#define NW 64

typedef __attribute__((ext_vector_type(8)))  short bf16x8;   // 8 bf16 in 4 VGPRs
typedef __attribute__((ext_vector_type(16))) float f32x16;   // 32x32 acc

__device__ __forceinline__ unsigned fmap(float f) {
    unsigned u = __float_as_uint(f);
    return (u & 0x80000000u) ? ~u : (u | 0x80000000u);
}
__device__ __forceinline__ float funmap(unsigned m) {
    unsigned u = (m & 0x80000000u) ? (m ^ 0x80000000u) : ~m;
    return __uint_as_float(u);
}
__device__ __forceinline__ float silu(float v) {
    return v / (1.0f + __expf(-v));
}
__device__ __forceinline__ unsigned short tobf(float f) {  // RNE f32->bf16
    unsigned u = __float_as_uint(f);
    u += 0x7FFFu + ((u >> 16) & 1u);
    return (unsigned short)(u >> 16);
}

__global__ void init_ws_kernel(unsigned* ws) {
    int t = threadIdx.x;
    if (t < 4) { ws[t * 2] = 0xFFFFFFFFu; ws[t * 2 + 1] = 0u; }
}

__global__ __launch_bounds__(256) void minmax_kernel(const float* __restrict__ x,
                                                     unsigned* __restrict__ ws) {
    int plane = blockIdx.x;          // b*64 + ch
    int ch = plane & 63;
    int g = ch >> 4;
    const float4* p = (const float4*)(x + (size_t)plane * 4096);
    int t = threadIdx.x;
    float mn = 3.4e38f, mx = -3.4e38f;
    #pragma unroll
    for (int k = 0; k < 4; ++k) {
        float4 v = p[t + k * 256];
        mn = fminf(mn, fminf(fminf(v.x, v.y), fminf(v.z, v.w)));
        mx = fmaxf(mx, fmaxf(fmaxf(v.x, v.y), fmaxf(v.z, v.w)));
    }
    #pragma unroll
    for (int off = 32; off; off >>= 1) {
        mn = fminf(mn, __shfl_xor(mn, off));
        mx = fmaxf(mx, __shfl_xor(mx, off));
    }
    __shared__ float smn[4], smx[4];
    int wid = t >> 6, lane = t & 63;
    if (lane == 0) { smn[wid] = mn; smx[wid] = mx; }
    __syncthreads();
    if (t == 0) {
        mn = fminf(fminf(smn[0], smn[1]), fminf(smn[2], smn[3]));
        mx = fmaxf(fmaxf(smx[0], smx[1]), fmaxf(smx[2], smx[3]));
        atomicMin(&ws[g * 2], fmap(mn));
        atomicMax(&ws[g * 2 + 1], fmap(mx));
    }
}

// wpk[tap][oc][k] bf16, tap=ky*3+kx (9), oc (32), k=aug-ch (80)
__global__ __launch_bounds__(256) void repack_kernel(const float* __restrict__ w,
                                                     unsigned short* __restrict__ wpk) {
    int idx = blockIdx.x * 256 + threadIdx.x;
    if (idx >= 23040) return;
    int tap = idx / 2560;
    int r = idx - tap * 2560;
    int oc = r / 80;
    int k = r - oc * 80;
    wpk[idx] = tobf(w[oc * 720 + k * 9 + tap]);
}

__global__ __launch_bounds__(512, 4) void conv_mfma_kernel(const float* __restrict__ x,
                                                           const unsigned* __restrict__ ws,
                                                           const unsigned short* __restrict__ wpk,
                                                           float* __restrict__ out) {
    int tile = blockIdx.x;   // 16 tiles of 16x16
    int b = blockIdx.y;
    int g = blockIdx.z;
    int th0 = (tile >> 2) * 16, tw0 = (tile & 3) * 16;

    // aug[pixel 0..323][k 0..87] bf16 ; pixel = hy*18+hx (halo coords), stride 88
    __shared__ unsigned short aug[324 * 88];     // 57024 B

    float xmin = funmap(ws[g * 2]);
    float xmax = funmap(ws[g * 2 + 1]);
    float inv = 2.0f / (xmax - xmin);

    const float* xg = x + ((size_t)b * 64 + g * 16) * 4096;
    int t = threadIdx.x;

    // ---- stage augmented tile: 16 c x 324 halo pixels -> 5 bf16 each ----
    for (int i = 0; i < 11; ++i) {
        int idx = t + i * 512;
        if (idx < 5184) {
            int c = idx / 324;
            int pix = idx - c * 324;
            int ly = pix / 18, lx = pix - ly * 18;
            int gh = th0 + ly - 1, gw = tw0 + lx - 1;
            bool ok = (gh >= 0 && gh < NH && gw >= 0 && gw < NW);
            float v = ok ? xg[c * 4096 + gh * 64 + gw] : 0.f;
            float s  = silu(v);                     // silu(0)=0
            float xn = (v - xmin) * inv - 1.f;
            float p2 = 1.5f * xn * xn - 0.5f;
            float p3 = (2.5f * xn * xn - 1.5f) * xn;
            int base = pix * 88 + c;
            aug[base]          = tobf(s);
            aug[base + 16]     = ok ? (unsigned short)0x3F80 : (unsigned short)0;
            aug[base + 32]     = ok ? tobf(xn) : (unsigned short)0;
            aug[base + 48]     = ok ? tobf(p2) : (unsigned short)0;
            aug[base + 64]     = ok ? tobf(p3) : (unsigned short)0;
        }
    }
    __syncthreads();

    // ---- MFMA: wave w owns rows 2w,2w+1 of the 16x16 tile (32 px) x 32 oc ----
    int w = t >> 6;
    int lane = t & 63;
    int lo = lane & 31, hi = lane >> 5;
    int py = 2 * w + (lo >> 4), px = lo & 15;     // A row = lane&31 -> pixel

    f32x16 acc = {};

    #pragma unroll
    for (int tap = 0; tap < 9; ++tap) {
        const int ky = tap / 3, kx = tap % 3;
        // B frags for this tap: wpk[(tap*32+oc)*80 + kc*16 + hi*8 .. +8]
        const bf16x8* bp = (const bf16x8*)(wpk + ((tap * 32 + lo) * 80 + hi * 8));
        bf16x8 Bf[5];
        #pragma unroll
        for (int kc = 0; kc < 5; ++kc) Bf[kc] = bp[2 * kc];
        // A frags: aug[((py+ky)*18 + (px+kx))*88 + kc*16 + hi*8]
        const unsigned short* ap = aug + (((py + ky) * 18 + (px + kx)) * 88 + hi * 8);
        #pragma unroll
        for (int kc = 0; kc < 5; ++kc) {
            bf16x8 Af = *(const bf16x8*)(ap + kc * 16);
            acc = __builtin_amdgcn_mfma_f32_32x32x16_bf16(Af, Bf[kc], acc, 0, 0, 0);
        }
    }

    // ---- epilogue: transpose via LDS for coalesced stores ----
    __syncthreads();                       // all A reads done before aliasing
    float* lout = (float*)aug;             // 32 x 257 floats = 32896 B
    #pragma unroll
    for (int r = 0; r < 16; ++r) {
        int m = (r & 3) + 8 * (r >> 2) + 4 * hi;   // D row (pixel within wave tile)
        lout[lo * 257 + w * 32 + m] = acc[r];
    }
    __syncthreads();
    size_t obase = ((size_t)b * 128 + g * 32) * 4096;
    #pragma unroll
    for (int i = 0; i < 16; ++i) {
        int idx = t + i * 512;             // 8192 = 32 oc x 256 px
        int oc = idx >> 8, p = idx & 255;
        float v = lout[oc * 257 + p];
        int m_blk_w = p >> 5;              // which wave tile
        int m = p & 31;
        int pyy = 2 * m_blk_w + (m >> 4), pxx = m & 15;
        out[obase + (size_t)oc * 4096 + (size_t)(th0 + pyy) * 64 + (tw0 + pxx)] = v;
    }
}

__global__ __launch_bounds__(256) void norm_kernel(float* __restrict__ out) {
    int plane = blockIdx.x;      // b*128 + ch
    float4* p = (float4*)(out + (size_t)plane * 4096);
    int t = threadIdx.x;
    float4 v[4];
    float s = 0.f, s2 = 0.f;
    #pragma unroll
    for (int k = 0; k < 4; ++k) {
        v[k] = p[t + k * 256];
        s  += v[k].x + v[k].y + v[k].z + v[k].w;
        s2 += v[k].x * v[k].x + v[k].y * v[k].y + v[k].z * v[k].z + v[k].w * v[k].w;
    }
    #pragma unroll
    for (int off = 32; off; off >>= 1) {
        s  += __shfl_xor(s, off);
        s2 += __shfl_xor(s2, off);
    }
    __shared__ float ss[4], ss2[4];
    int wid = t >> 6, lane = t & 63;
    if (lane == 0) { ss[wid] = s; ss2[wid] = s2; }
    __syncthreads();
    s  = ss[0] + ss[1] + ss[2] + ss[3];
    s2 = ss2[0] + ss2[1] + ss2[2] + ss2[3];
    float mean = s * (1.f / 4096.f);
    float var  = fmaxf(s2 * (1.f / 4096.f) - mean * mean, 0.f);
    float istd = rsqrtf(var + 1e-5f);
    #pragma unroll
    for (int k = 0; k < 4; ++k) {
        float4 o;
        o.x = (v[k].x - mean) * istd; o.x = silu(o.x);
        o.y = (v[k].y - mean) * istd; o.y = silu(o.y);
        o.z = (v[k].z - mean) * istd; o.z = silu(o.z);
        o.w = (v[k].w - mean) * istd; o.w = silu(o.w);
        p[t + k * 256] = o;
    }
}

extern "C" void kernel_launch(void* const* d_in, const int* in_sizes, int n_in,
                              void* d_out, int out_size, void* d_ws, size_t ws_size,
                              hipStream_t stream) {
    const float* x = (const float*)d_in[0];
    const float* w = (const float*)d_in[1];
    float* out = (float*)d_out;
    unsigned* ws = (unsigned*)d_ws;
    unsigned short* wpk = (unsigned short*)((char*)d_ws + 64);

    hipLaunchKernelGGL(init_ws_kernel, dim3(1), dim3(64), 0, stream, ws);
    hipLaunchKernelGGL(minmax_kernel, dim3(NB * 64), dim3(256), 0, stream, x, ws);
    hipLaunchKernelGGL(repack_kernel, dim3(90), dim3(256), 0, stream, w, wpk);
    hipLaunchKernelGGL(conv_mfma_kernel, dim3(16, NB, 4), dim3(512), 0, stream, x, ws, wpk, out);
    hipLaunchKernelGGL(norm_kernel, dim3(NB * 128), dim3(256), 0, stream, out);
}

// Round 3
// 272.504 us; speedup vs baseline: 4.2372x; 1.0172x over previous
//
#include <hip/hip_runtime.h>
#include <hip/hip_bf16.h>

// SimpleMetaConvKALN: x (64,64,64,64) f32, w (32,80,3,3) f32 -> out (64,128,64,64) f32
// Augmented-input view per group g (16 in-ch), k = d*16+c, d in {silu,1,xn,P2,P3}:
//   y = conv3x3(A, w) == sum over 9 taps of shifted GEMM (M=32 oc, N=px, K=80)
//   then instance-norm over HxW per (b,oc), then silu.
// A = weights (rows=oc), B = aug tile in LDS chunk-major [kc][pix][8] (cols=px)
// -> D[oc][px] stores straight to global, no epilogue transpose.

#define NB 64
#define NH 64
#define NW 64

typedef __attribute__((ext_vector_type(8)))  short bf16x8;   // 8 bf16 = 4 VGPRs
typedef __attribute__((ext_vector_type(16))) float f32x16;   // 32x32 acc

__device__ __forceinline__ unsigned fmap(float f) {
    unsigned u = __float_as_uint(f);
    return (u & 0x80000000u) ? ~u : (u | 0x80000000u);
}
__device__ __forceinline__ float funmap(unsigned m) {
    unsigned u = (m & 0x80000000u) ? (m ^ 0x80000000u) : ~m;
    return __uint_as_float(u);
}
__device__ __forceinline__ float silu(float v) {
    return v / (1.0f + __expf(-v));
}
__device__ __forceinline__ unsigned short tobf(float f) {  // RNE f32->bf16
    unsigned u = __float_as_uint(f);
    u += 0x7FFFu + ((u >> 16) & 1u);
    return (unsigned short)(u >> 16);
}

__global__ void init_ws_kernel(unsigned* ws) {
    int t = threadIdx.x;
    if (t < 4) { ws[t * 2] = 0xFFFFFFFFu; ws[t * 2 + 1] = 0u; }
}

__global__ __launch_bounds__(256) void minmax_kernel(const float* __restrict__ x,
                                                     unsigned* __restrict__ ws) {
    int plane = blockIdx.x;          // b*64 + ch
    int ch = plane & 63;
    int g = ch >> 4;
    const float4* p = (const float4*)(x + (size_t)plane * 4096);
    int t = threadIdx.x;
    float mn = 3.4e38f, mx = -3.4e38f;
    #pragma unroll
    for (int k = 0; k < 4; ++k) {
        float4 v = p[t + k * 256];
        mn = fminf(mn, fminf(fminf(v.x, v.y), fminf(v.z, v.w)));
        mx = fmaxf(mx, fmaxf(fmaxf(v.x, v.y), fmaxf(v.z, v.w)));
    }
    #pragma unroll
    for (int off = 32; off; off >>= 1) {
        mn = fminf(mn, __shfl_xor(mn, off));
        mx = fmaxf(mx, __shfl_xor(mx, off));
    }
    __shared__ float smn[4], smx[4];
    int wid = t >> 6, lane = t & 63;
    if (lane == 0) { smn[wid] = mn; smx[wid] = mx; }
    __syncthreads();
    if (t == 0) {
        mn = fminf(fminf(smn[0], smn[1]), fminf(smn[2], smn[3]));
        mx = fmaxf(fmaxf(smx[0], smx[1]), fmaxf(smx[2], smx[3]));
        atomicMin(&ws[g * 2], fmap(mn));
        atomicMax(&ws[g * 2 + 1], fmap(mx));
    }
}

// wpk[tap][oc][k] bf16, tap=ky*3+kx (9), oc (32), k=aug-ch (80)
__global__ __launch_bounds__(256) void repack_kernel(const float* __restrict__ w,
                                                     unsigned short* __restrict__ wpk) {
    int idx = blockIdx.x * 256 + threadIdx.x;
    if (idx >= 23040) return;
    int tap = idx / 2560;
    int r = idx - tap * 2560;
    int oc = r / 80;
    int k = r - oc * 80;
    wpk[idx] = tobf(w[oc * 720 + k * 9 + tap]);
}

__global__ __launch_bounds__(512, 6) void conv_mfma_kernel(const float* __restrict__ x,
                                                           const unsigned* __restrict__ ws,
                                                           const unsigned short* __restrict__ wpk,
                                                           float* __restrict__ out) {
    int tile = blockIdx.x;   // 16 tiles of 16x16
    int b = blockIdx.y;
    int g = blockIdx.z;
    int th0 = (tile >> 2) * 16, tw0 = (tile & 3) * 16;

    // chunk-major: aug[kc 0..9][pix 0..323][8 bf16]; kc = (d*16+c)>>3
    __shared__ unsigned short aug[10 * 324 * 8];   // 51840 B

    float xmin = funmap(ws[g * 2]);
    float xmax = funmap(ws[g * 2 + 1]);
    float inv = 2.0f / (xmax - xmin);

    const float* xg = x + ((size_t)b * 64 + g * 16) * 4096;
    int t = threadIdx.x;

    // ---- stage: 5 task-kinds x 324 halo pixels; all LDS writes are b128 ----
    // kind 0: silu c0-7 -> kc0 ; kind 1: silu c8-15 -> kc1
    // kind 2: poly c0-7 -> kc4,6,8 ; kind 3: poly c8-15 -> kc5,7,9
    // kind 4: ones -> kc2,kc3
    #pragma unroll
    for (int i = 0; i < 4; ++i) {
        int idx = t + i * 512;
        if (idx < 1620) {
            int kind = idx / 324;
            int pix = idx - kind * 324;
            int ly = pix / 18, lx = pix - ly * 18;
            int gh = th0 + ly - 1, gw = tw0 + lx - 1;
            bool ok = (gh >= 0 && gh < NH && gw >= 0 && gw < NW);
            const float* src = xg + gh * 64 + gw;
            if (kind == 4) {
                unsigned short o = ok ? (unsigned short)0x3F80 : (unsigned short)0;
                bf16x8 v;
                #pragma unroll
                for (int j = 0; j < 8; ++j) v[j] = (short)o;
                *(bf16x8*)&aug[(2 * 324 + pix) * 8] = v;
                *(bf16x8*)&aug[(3 * 324 + pix) * 8] = v;
            } else if (kind < 2) {
                int c0 = kind * 8;
                bf16x8 v;
                #pragma unroll
                for (int j = 0; j < 8; ++j) {
                    float val = ok ? src[(size_t)(c0 + j) * 4096] : 0.f;
                    v[j] = (short)tobf(silu(val));
                }
                *(bf16x8*)&aug[(kind * 324 + pix) * 8] = v;
            } else {
                int half = kind & 1;           // kind2 -> c0-7, kind3 -> c8-15
                int c0 = half * 8;
                bf16x8 v1, v2, v3;
                #pragma unroll
                for (int j = 0; j < 8; ++j) {
                    float val = ok ? src[(size_t)(c0 + j) * 4096] : 0.f;
                    float xn = (val - xmin) * inv - 1.f;
                    float p2 = 1.5f * xn * xn - 0.5f;
                    float p3 = (2.5f * xn * xn - 1.5f) * xn;
                    v1[j] = ok ? (short)tobf(xn) : (short)0;
                    v2[j] = ok ? (short)tobf(p2) : (short)0;
                    v3[j] = ok ? (short)tobf(p3) : (short)0;
                }
                *(bf16x8*)&aug[((4 + half) * 324 + pix) * 8] = v1;
                *(bf16x8*)&aug[((6 + half) * 324 + pix) * 8] = v2;
                *(bf16x8*)&aug[((8 + half) * 324 + pix) * 8] = v3;
            }
        }
    }
    __syncthreads();

    // ---- MFMA: wave w owns pixels [32w, 32w+32) x all 32 oc ----
    int w = t >> 6;
    int lane = t & 63;
    int lo = lane & 31, hi = lane >> 5;
    int py = 2 * w + (lo >> 4), px = lo & 15;   // B col = pixel

    f32x16 acc = {};

    #pragma unroll
    for (int tap = 0; tap < 9; ++tap) {
        const int ky = tap / 3, kx = tap % 3;
        int hp = (py + ky) * 18 + (px + kx);    // halo pixel index
        const unsigned short* wbase = wpk + ((size_t)(tap * 32 + lo) * 80 + hi * 8);
        #pragma unroll
        for (int kc = 0; kc < 5; ++kc) {
            bf16x8 Af = *(const bf16x8*)(wbase + kc * 16);              // A: w[oc=lo][k]
            bf16x8 Bf = *(const bf16x8*)&aug[((kc * 2 + hi) * 324 + hp) * 8]; // B: aug[k][px=lo]
            acc = __builtin_amdgcn_mfma_f32_32x32x16_bf16(Af, Bf, acc, 0, 0, 0);
        }
    }

    // ---- direct coalesced stores: D[row=oc][col=px] ----
    size_t obase = ((size_t)b * 128 + g * 32) * 4096 + (size_t)(th0 + py) * 64 + (tw0 + px);
    #pragma unroll
    for (int r = 0; r < 16; ++r) {
        int oc = (r & 3) + 8 * (r >> 2) + 4 * hi;
        out[obase + (size_t)oc * 4096] = acc[r];
    }
}

__global__ __launch_bounds__(256) void norm_kernel(float* __restrict__ out) {
    int plane = blockIdx.x;      // b*128 + ch
    float4* p = (float4*)(out + (size_t)plane * 4096);
    int t = threadIdx.x;
    float4 v[4];
    float s = 0.f, s2 = 0.f;
    #pragma unroll
    for (int k = 0; k < 4; ++k) {
        v[k] = p[t + k * 256];
        s  += v[k].x + v[k].y + v[k].z + v[k].w;
        s2 += v[k].x * v[k].x + v[k].y * v[k].y + v[k].z * v[k].z + v[k].w * v[k].w;
    }
    #pragma unroll
    for (int off = 32; off; off >>= 1) {
        s  += __shfl_xor(s, off);
        s2 += __shfl_xor(s2, off);
    }
    __shared__ float ss[4], ss2[4];
    int wid = t >> 6, lane = t & 63;
    if (lane == 0) { ss[wid] = s; ss2[wid] = s2; }
    __syncthreads();
    s  = ss[0] + ss[1] + ss[2] + ss[3];
    s2 = ss2[0] + ss2[1] + ss2[2] + ss2[3];
    float mean = s * (1.f / 4096.f);
    float var  = fmaxf(s2 * (1.f / 4096.f) - mean * mean, 0.f);
    float istd = rsqrtf(var + 1e-5f);
    #pragma unroll
    for (int k = 0; k < 4; ++k) {
        float4 o;
        o.x = (v[k].x - mean) * istd; o.x = silu(o.x);
        o.y = (v[k].y - mean) * istd; o.y = silu(o.y);
        o.z = (v[k].z - mean) * istd; o.z = silu(o.z);
        o.w = (v[k].w - mean) * istd; o.w = silu(o.w);
        p[t + k * 256] = o;
    }
}

extern "C" void kernel_launch(void* const* d_in, const int* in_sizes, int n_in,
                              void* d_out, int out_size, void* d_ws, size_t ws_size,
                              hipStream_t stream) {
    const float* x = (const float*)d_in[0];
    const float* w = (const float*)d_in[1];
    float* out = (float*)d_out;
    unsigned* ws = (unsigned*)d_ws;
    unsigned short* wpk = (unsigned short*)((char*)d_ws + 64);

    hipLaunchKernelGGL(init_ws_kernel, dim3(1), dim3(64), 0, stream, ws);
    hipLaunchKernelGGL(minmax_kernel, dim3(NB * 64), dim3(256), 0, stream, x, ws);
    hipLaunchKernelGGL(repack_kernel, dim3(90), dim3(256), 0, stream, w, wpk);
    hipLaunchKernelGGL(conv_mfma_kernel, dim3(16, NB, 4), dim3(512), 0, stream, x, ws, wpk, out);
    hipLaunchKernelGGL(norm_kernel, dim3(NB * 128), dim3(256), 0, stream, out);
}

// Round 4
// 167.417 us; speedup vs baseline: 6.8968x; 1.6277x over previous
//
#include <hip/hip_runtime.h>
#include <hip/hip_bf16.h>

// SimpleMetaConvKALN: x (64,64,64,64) f32, w (32,80,3,3) f32 -> out (64,128,64,64) f32
// y = conv3x3(aug(x), w) per group; instance-norm per (b,oc); silu.
// A = weights (rows=oc) in per-tap double-buffered registers,
// B = aug tile in LDS chunk-major [kc][pix][8] -> D[oc][px] direct stores.

#define NB 64
#define NH 64
#define NW 64

typedef __attribute__((ext_vector_type(8)))  short bf16x8;
typedef __attribute__((ext_vector_type(16))) float f32x16;

__device__ __forceinline__ float silu(float v) {
    return v / (1.0f + __expf(-v));
}
__device__ __forceinline__ unsigned short tobf(float f) {  // RNE f32->bf16
    unsigned u = __float_as_uint(f);
    u += 0x7FFFu + ((u >> 16) & 1u);
    return (unsigned short)(u >> 16);
}

// ---- per-plane min/max (no atomics) ----
__global__ __launch_bounds__(256) void minmax_kernel(const float* __restrict__ x,
                                                     float* __restrict__ pmm) {
    int plane = blockIdx.x;          // b*64 + ch
    const float4* p = (const float4*)(x + (size_t)plane * 4096);
    int t = threadIdx.x;
    float mn = 3.4e38f, mx = -3.4e38f;
    #pragma unroll
    for (int k = 0; k < 4; ++k) {
        float4 v = p[t + k * 256];
        mn = fminf(mn, fminf(fminf(v.x, v.y), fminf(v.z, v.w)));
        mx = fmaxf(mx, fmaxf(fmaxf(v.x, v.y), fmaxf(v.z, v.w)));
    }
    #pragma unroll
    for (int off = 32; off; off >>= 1) {
        mn = fminf(mn, __shfl_xor(mn, off));
        mx = fmaxf(mx, __shfl_xor(mx, off));
    }
    __shared__ float smn[4], smx[4];
    int wid = t >> 6, lane = t & 63;
    if (lane == 0) { smn[wid] = mn; smx[wid] = mx; }
    __syncthreads();
    if (t == 0) {
        mn = fminf(fminf(smn[0], smn[1]), fminf(smn[2], smn[3]));
        mx = fmaxf(fmaxf(smx[0], smx[1]), fmaxf(smx[2], smx[3]));
        pmm[plane * 2]     = mn;
        pmm[plane * 2 + 1] = mx;
    }
}

// blocks 0-3: reduce pmm -> wsf[g]; blocks 4-93: repack weights to bf16 [tap][oc][k]
__global__ __launch_bounds__(256) void reduce_repack_kernel(const float* __restrict__ pmm,
                                                            const float* __restrict__ w,
                                                            float* __restrict__ wsf,
                                                            unsigned short* __restrict__ wpk) {
    int blk = blockIdx.x;
    int t = threadIdx.x;
    if (blk < 4) {
        int g = blk;
        float mn = 3.4e38f, mx = -3.4e38f;
        #pragma unroll
        for (int j = 0; j < 4; ++j) {
            int p = t + j * 256;             // 0..1023
            int b = p >> 4, c = p & 15;
            int plane = b * 64 + g * 16 + c;
            mn = fminf(mn, pmm[plane * 2]);
            mx = fmaxf(mx, pmm[plane * 2 + 1]);
        }
        #pragma unroll
        for (int off = 32; off; off >>= 1) {
            mn = fminf(mn, __shfl_xor(mn, off));
            mx = fmaxf(mx, __shfl_xor(mx, off));
        }
        __shared__ float smn[4], smx[4];
        int wid = t >> 6, lane = t & 63;
        if (lane == 0) { smn[wid] = mn; smx[wid] = mx; }
        __syncthreads();
        if (t == 0) {
            mn = fminf(fminf(smn[0], smn[1]), fminf(smn[2], smn[3]));
            mx = fmaxf(fmaxf(smx[0], smx[1]), fmaxf(smx[2], smx[3]));
            wsf[g * 2]     = mn;
            wsf[g * 2 + 1] = mx;
        }
    } else {
        int idx = (blk - 4) * 256 + t;
        if (idx < 23040) {
            int tap = idx / 2560;
            int r = idx - tap * 2560;
            int oc = r / 80;
            int k = r - oc * 80;
            wpk[idx] = tobf(w[oc * 720 + k * 9 + tap]);
        }
    }
}

__global__ __launch_bounds__(512, 4) void conv_mfma_kernel(const float* __restrict__ x,
                                                           const float* __restrict__ wsf,
                                                           const unsigned short* __restrict__ wpk,
                                                           float* __restrict__ out) {
    // XCD swizzle: consecutive work-chunks of 512 land on one XCD
    int flat = blockIdx.x;                       // 0..4095
    int f = ((flat & 7) << 9) | (flat >> 3);     // bijective
    int tile = f & 15;
    int bg = f >> 4;
    int b = bg & 63;
    int g = bg >> 6;
    int th0 = (tile >> 2) * 16, tw0 = (tile & 3) * 16;

    // chunk-major: aug[kc 0..9][pix 0..323][8 bf16]
    __shared__ unsigned short aug[10 * 324 * 8];   // 51840 B

    float xmin = wsf[g * 2];
    float xmax = wsf[g * 2 + 1];
    float inv = 2.0f / (xmax - xmin);

    const float* xg = x + ((size_t)b * 64 + g * 16) * 4096;
    int t = threadIdx.x;

    // ---- stage augmented tile (all LDS writes are b128) ----
    #pragma unroll
    for (int i = 0; i < 4; ++i) {
        int idx = t + i * 512;
        if (idx < 1620) {
            int kind = idx / 324;
            int pix = idx - kind * 324;
            int ly = pix / 18, lx = pix - ly * 18;
            int gh = th0 + ly - 1, gw = tw0 + lx - 1;
            bool ok = (gh >= 0 && gh < NH && gw >= 0 && gw < NW);
            const float* src = xg + gh * 64 + gw;
            if (kind == 4) {
                unsigned short o = ok ? (unsigned short)0x3F80 : (unsigned short)0;
                bf16x8 v;
                #pragma unroll
                for (int j = 0; j < 8; ++j) v[j] = (short)o;
                *(bf16x8*)&aug[(2 * 324 + pix) * 8] = v;
                *(bf16x8*)&aug[(3 * 324 + pix) * 8] = v;
            } else if (kind < 2) {
                int c0 = kind * 8;
                bf16x8 v;
                #pragma unroll
                for (int j = 0; j < 8; ++j) {
                    float val = ok ? src[(size_t)(c0 + j) * 4096] : 0.f;
                    v[j] = (short)tobf(silu(val));
                }
                *(bf16x8*)&aug[(kind * 324 + pix) * 8] = v;
            } else {
                int half = kind & 1;
                int c0 = half * 8;
                bf16x8 v1, v2, v3;
                #pragma unroll
                for (int j = 0; j < 8; ++j) {
                    float val = ok ? src[(size_t)(c0 + j) * 4096] : 0.f;
                    float xn = (val - xmin) * inv - 1.f;
                    float p2 = 1.5f * xn * xn - 0.5f;
                    float p3 = (2.5f * xn * xn - 1.5f) * xn;
                    v1[j] = ok ? (short)tobf(xn) : (short)0;
                    v2[j] = ok ? (short)tobf(p2) : (short)0;
                    v3[j] = ok ? (short)tobf(p3) : (short)0;
                }
                *(bf16x8*)&aug[((4 + half) * 324 + pix) * 8] = v1;
                *(bf16x8*)&aug[((6 + half) * 324 + pix) * 8] = v2;
                *(bf16x8*)&aug[((8 + half) * 324 + pix) * 8] = v3;
            }
        }
    }
    __syncthreads();

    // ---- MFMA with per-tap double-buffered weight registers ----
    int wv = t >> 6;
    int lane = t & 63;
    int lo = lane & 31, hi = lane >> 5;
    int py = 2 * wv + (lo >> 4), px = lo & 15;   // B col = pixel

    const bf16x8* wp = (const bf16x8*)wpk;       // frag (tap,kc): (tap*32+lo)*10 + hi + kc*2

    f32x16 acc = {};
    bf16x8 W[2][5];
    #pragma unroll
    for (int kc = 0; kc < 5; ++kc) W[0][kc] = wp[lo * 10 + hi + kc * 2];

    #pragma unroll
    for (int tap = 0; tap < 9; ++tap) {
        const int cur = tap & 1, nxt = cur ^ 1;
        if (tap < 8) {
            #pragma unroll
            for (int kc = 0; kc < 5; ++kc)
                W[nxt][kc] = wp[((tap + 1) * 32 + lo) * 10 + hi + kc * 2];
        }
        const int ky = tap / 3, kx = tap % 3;
        const int hp = (py + ky) * 18 + (px + kx);
        #pragma unroll
        for (int kc = 0; kc < 5; ++kc) {
            bf16x8 Bf = *(const bf16x8*)&aug[(((kc * 2 + hi) * 324) + hp) * 8];
            acc = __builtin_amdgcn_mfma_f32_32x32x16_bf16(W[cur][kc], Bf, acc, 0, 0, 0);
        }
    }

    // ---- direct coalesced stores: D[row=oc][col=px] ----
    size_t obase = ((size_t)b * 128 + g * 32) * 4096 + (size_t)(th0 + py) * 64 + (tw0 + px);
    #pragma unroll
    for (int r = 0; r < 16; ++r) {
        int oc = (r & 3) + 8 * (r >> 2) + 4 * hi;
        out[obase + (size_t)oc * 4096] = acc[r];
    }
}

__global__ __launch_bounds__(256) void norm_kernel(float* __restrict__ out) {
    int plane = blockIdx.x;      // b*128 + ch
    float4* p = (float4*)(out + (size_t)plane * 4096);
    int t = threadIdx.x;
    float4 v[4];
    float s = 0.f, s2 = 0.f;
    #pragma unroll
    for (int k = 0; k < 4; ++k) {
        v[k] = p[t + k * 256];
        s  += v[k].x + v[k].y + v[k].z + v[k].w;
        s2 += v[k].x * v[k].x + v[k].y * v[k].y + v[k].z * v[k].z + v[k].w * v[k].w;
    }
    #pragma unroll
    for (int off = 32; off; off >>= 1) {
        s  += __shfl_xor(s, off);
        s2 += __shfl_xor(s2, off);
    }
    __shared__ float ss[4], ss2[4];
    int wid = t >> 6, lane = t & 63;
    if (lane == 0) { ss[wid] = s; ss2[wid] = s2; }
    __syncthreads();
    s  = ss[0] + ss[1] + ss[2] + ss[3];
    s2 = ss2[0] + ss2[1] + ss2[2] + ss2[3];
    float mean = s * (1.f / 4096.f);
    float var  = fmaxf(s2 * (1.f / 4096.f) - mean * mean, 0.f);
    float istd = rsqrtf(var + 1e-5f);
    #pragma unroll
    for (int k = 0; k < 4; ++k) {
        float4 o;
        o.x = (v[k].x - mean) * istd; o.x = silu(o.x);
        o.y = (v[k].y - mean) * istd; o.y = silu(o.y);
        o.z = (v[k].z - mean) * istd; o.z = silu(o.z);
        o.w = (v[k].w - mean) * istd; o.w = silu(o.w);
        p[t + k * 256] = o;
    }
}

extern "C" void kernel_launch(void* const* d_in, const int* in_sizes, int n_in,
                              void* d_out, int out_size, void* d_ws, size_t ws_size,
                              hipStream_t stream) {
    const float* x = (const float*)d_in[0];
    const float* w = (const float*)d_in[1];
    float* out = (float*)d_out;
    float* wsf = (float*)d_ws;                                   // 8 floats
    float* pmm = (float*)((char*)d_ws + 64);                     // 4096*2 floats
    unsigned short* wpk = (unsigned short*)((char*)d_ws + 64 + 32768);  // 23040 bf16

    hipLaunchKernelGGL(minmax_kernel, dim3(NB * 64), dim3(256), 0, stream, x, pmm);
    hipLaunchKernelGGL(reduce_repack_kernel, dim3(94), dim3(256), 0, stream, pmm, w, wsf, wpk);
    hipLaunchKernelGGL(conv_mfma_kernel, dim3(4096), dim3(512), 0, stream, x, wsf, wpk, out);
    hipLaunchKernelGGL(norm_kernel, dim3(NB * 128), dim3(256), 0, stream, out);
}